// Round 1
// baseline (2376.921 us; speedup 1.0000x reference)
//
#include <hip/hip_runtime.h>

typedef unsigned int  u32;
typedef unsigned short u16;
typedef _Float16 h2_t  __attribute__((ext_vector_type(2)));
typedef short   short8 __attribute__((ext_vector_type(8)));
typedef float   f32x4  __attribute__((ext_vector_type(4)));

#define T_LEN 512
#define BATCH 64
#define EDIM  256
#define HDIM  256
#define G4    1024   // 4*H gate rows

// ---------- numeric helpers ----------
static __device__ __forceinline__ u16 f2bf(float f) {
  u32 u = __builtin_bit_cast(u32, f);
  u = (u + 0x7fffu + ((u >> 16) & 1u)) >> 16;   // RTNE
  return (u16)u;
}
static __device__ __forceinline__ float bf2f(u16 b) {
  return __builtin_bit_cast(float, (u32)b << 16);
}
static __device__ __forceinline__ u32 packh2(float a, float b) {
  _Float16 ha = (_Float16)a, hb = (_Float16)b;
  u16 ua = __builtin_bit_cast(u16, ha), ub = __builtin_bit_cast(u16, hb);
  return (u32)ua | ((u32)ub << 16);
}
static __device__ __forceinline__ u16 f2h(float a) {
  _Float16 ha = (_Float16)a;
  return __builtin_bit_cast(u16, ha);
}
static __device__ __forceinline__ float dot2(u32 w, u32 h, float c) {
#if __has_builtin(__builtin_amdgcn_fdot2)
  return __builtin_amdgcn_fdot2(__builtin_bit_cast(h2_t, w),
                                __builtin_bit_cast(h2_t, h), c, false);
#else
  h2_t a = __builtin_bit_cast(h2_t, w), b = __builtin_bit_cast(h2_t, h);
  return c + (float)a.x * (float)b.x + (float)a.y * (float)b.y;
#endif
}
static __device__ __forceinline__ float sigf(float x) {
  return 1.0f / (1.0f + __expf(-x));
}
static __device__ __forceinline__ float tanhfast(float x) {
  return 2.0f / (1.0f + __expf(-2.0f * x)) - 1.0f;
}

// ---------- kernel 1: pack W_hh_f into fp16, k-major uint4 layout ----------
// Wp layout (as u32): [kk4 0..31][g 0..1023][j 0..3]; u32 (kk4,g,j) holds
// half2 of W_hh[g][2*(4*kk4+j)], W_hh[g][2*(4*kk4+j)+1].
__global__ __launch_bounds__(256) void k_prep(const float* __restrict__ whh,
                                              u32* __restrict__ Wp) {
  int id = blockIdx.x * 256 + threadIdx.x;   // 131072 total = g*128 + kk
  int g = id >> 7, kk = id & 127;
  float a = whh[g * 256 + 2 * kk];
  float b = whh[g * 256 + 2 * kk + 1];
  Wp[(kk >> 2) * 4096 + g * 4 + (kk & 3)] = packh2(a, b);
}

// ---------- kernel 2: xproj = bf16-MFMA( emb[x] , W_ih_f^T ) + bias ----------
// grid (16, 512): blockIdx.x = N-tile (64 gate cols), blockIdx.y = t.
// M-tile of 64 == the 64 batch rows at timestep t.
#define LDSPITCH 264   // 256 + 8 bf16 pad, keeps 16B alignment, breaks bank aliasing
__global__ __launch_bounds__(256) void k_xproj(const int* __restrict__ x,
                                               const float* __restrict__ emb,
                                               const float* __restrict__ wih,
                                               const float* __restrict__ bih,
                                               const float* __restrict__ bhh,
                                               u16* __restrict__ xp) {
  __shared__ u16 smA[64 * LDSPITCH];
  __shared__ u16 smB[64 * LDSPITCH];
  const int tn = blockIdx.x, t = blockIdx.y;
  const int tid = threadIdx.x;
  const int r = tid >> 2, q4 = tid & 3;      // 4 threads per row, 64 elems each

  { // stage A: emb rows for batch r at timestep t  (fp32 -> bf16)
    int eidx = x[r * T_LEN + t];
    const float4* src = (const float4*)(emb + (long)eidx * EDIM + q4 * 64);
    u16* dst = smA + r * LDSPITCH + q4 * 64;
    #pragma unroll
    for (int i = 0; i < 16; ++i) {
      float4 v = src[i];
      uint2 p;
      p.x = (u32)f2bf(v.x) | ((u32)f2bf(v.y) << 16);
      p.y = (u32)f2bf(v.z) | ((u32)f2bf(v.w) << 16);
      *(uint2*)&dst[i * 4] = p;
    }
  }
  { // stage B: w_ih rows g = tn*64 + r
    const float4* src = (const float4*)(wih + (long)(tn * 64 + r) * EDIM + q4 * 64);
    u16* dst = smB + r * LDSPITCH + q4 * 64;
    #pragma unroll
    for (int i = 0; i < 16; ++i) {
      float4 v = src[i];
      uint2 p;
      p.x = (u32)f2bf(v.x) | ((u32)f2bf(v.y) << 16);
      p.y = (u32)f2bf(v.z) | ((u32)f2bf(v.w) << 16);
      *(uint2*)&dst[i * 4] = p;
    }
  }
  __syncthreads();

  const int wv = tid >> 6, lane = tid & 63;
  const int lm = lane & 15, q = lane >> 4;
  f32x4 acc[4];
  #pragma unroll
  for (int nt = 0; nt < 4; ++nt) acc[nt] = (f32x4){0.f, 0.f, 0.f, 0.f};

  const u16* pa = smA + (wv * 16 + lm) * LDSPITCH + q * 8;
  const u16* pb = smB + lm * LDSPITCH + q * 8;
  #pragma unroll
  for (int ks = 0; ks < 8; ++ks) {
    short8 av = *(const short8*)(pa + ks * 32);
    #pragma unroll
    for (int nt = 0; nt < 4; ++nt) {
      short8 bv = *(const short8*)(pb + nt * 16 * LDSPITCH + ks * 32);
      acc[nt] = __builtin_amdgcn_mfma_f32_16x16x32_bf16(av, bv, acc[nt], 0, 0, 0);
    }
  }
  // epilogue: D row = q*4+reg (batch), col = lm (gate)  [m89-verified mapping]
  #pragma unroll
  for (int nt = 0; nt < 4; ++nt) {
    int g = tn * 64 + nt * 16 + lm;
    float bias = bih[g] + bhh[g];
    #pragma unroll
    for (int rr = 0; rr < 4; ++rr) {
      int brow = wv * 16 + q * 4 + rr;                  // batch index
      xp[((long)t * BATCH + brow) * G4 + g] = f2bf(acc[nt][rr] + bias);
    }
  }
}

// ---------- kernel 3: forward LSTM recurrence, 1 WG per batch element ----------
__global__ __launch_bounds__(1024) void k_lstm(const uint4* __restrict__ Wp,
                                               const u16* __restrict__ xp,
                                               float* __restrict__ hf) {
  const int b = blockIdx.x;
  const int t = threadIdx.x;          // gate-row 0..1023
  __shared__ __align__(16) u16 h1[HDIM];   // h as fp16
  __shared__ float zbuf[G4];
  float c = 0.f;
  if (t < HDIM) h1[t] = 0;
  __syncthreads();

  for (int step = 0; step < T_LEN; ++step) {
    // prefetch this step's input projection early (HBM latency hide)
    float z = bf2f(xp[((long)step * BATCH + b) * G4 + t]);
    const uint4* hv4 = (const uint4*)h1;
    #pragma unroll 8
    for (int kk = 0; kk < 32; ++kk) {
      uint4 w = Wp[kk * 1024 + t];   // coalesced: consecutive t -> consecutive 16B
      uint4 h = hv4[kk];             // LDS broadcast
      z = dot2(w.x, h.x, z);
      z = dot2(w.y, h.y, z);
      z = dot2(w.z, h.z, z);
      z = dot2(w.w, h.w, z);
    }
    zbuf[t] = z;
    __syncthreads();
    if (t < HDIM) {
      float zi = zbuf[t], zf = zbuf[HDIM + t];
      float zg = zbuf[2 * HDIM + t], zo = zbuf[3 * HDIM + t];
      c = sigf(zf) * c + sigf(zi) * tanhfast(zg);
      float hn = sigf(zo) * tanhfast(c);
      h1[t] = f2h(hn);
      if (step == T_LEN - 1) hf[b * HDIM + t] = hn;
    }
    __syncthreads();
  }
}

// ---------- kernel 4: backward single step + fc1 + fc2 ----------
__global__ __launch_bounds__(256) void k_tail(const int* __restrict__ x,
                                              const float* __restrict__ emb,
                                              const float* __restrict__ wihb,
                                              const float* __restrict__ bihb,
                                              const float* __restrict__ bhhb,
                                              const float* __restrict__ fc1w,
                                              const float* __restrict__ fc1b,
                                              const float* __restrict__ fc2w,
                                              const float* __restrict__ fc2b,
                                              const float* __restrict__ hf,
                                              float* __restrict__ out) {
  const int b = blockIdx.x, tid = threadIdx.x;
  __shared__ float e[EDIM], hb[HDIM], hfl[HDIM], f1[24];
  e[tid]   = emb[(long)x[b * T_LEN + (T_LEN - 1)] * EDIM + tid];
  hfl[tid] = hf[b * HDIM + tid];
  __syncthreads();

  float z[4];
  #pragma unroll
  for (int gq = 0; gq < 4; ++gq) {
    int g = gq * HDIM + tid;
    float s = bihb[g] + bhhb[g];
    const float4* wr = (const float4*)(wihb + (long)g * EDIM);
    #pragma unroll 8
    for (int k = 0; k < 64; ++k) {
      float4 w = wr[k];
      s += w.x * e[4 * k] + w.y * e[4 * k + 1] + w.z * e[4 * k + 2] + w.w * e[4 * k + 3];
    }
    z[gq] = s;
  }
  // one LSTM step from zero state: c0=0 so forget-gate term vanishes
  float cb = sigf(z[0]) * tanhfast(z[2]);
  hb[tid] = sigf(z[3]) * tanhfast(cb);
  __syncthreads();

  if (tid < 24) {
    float s = fc1b[tid];
    const float* w = fc1w + tid * 512;
    #pragma unroll 8
    for (int k = 0; k < HDIM; ++k) s += w[k] * hfl[k] + w[HDIM + k] * hb[k];
    f1[tid] = fmaxf(s, 0.f);
  }
  __syncthreads();
  if (tid < 2) {
    float s = fc2b[tid];
    #pragma unroll
    for (int k = 0; k < 24; ++k) s += fc2w[tid * 24 + k] * f1[k];
    out[b * 2 + tid] = s;
  }
}

// ---------- launch ----------
extern "C" void kernel_launch(void* const* d_in, const int* in_sizes, int n_in,
                              void* d_out, int out_size, void* d_ws, size_t ws_size,
                              hipStream_t stream) {
  const int*   x     = (const int*)  d_in[0];
  const float* emb   = (const float*)d_in[1];
  const float* wih_f = (const float*)d_in[2];
  const float* whh_f = (const float*)d_in[3];
  const float* bih_f = (const float*)d_in[4];
  const float* bhh_f = (const float*)d_in[5];
  const float* wih_b = (const float*)d_in[6];
  // d_in[7] = w_hh_b: unused (backward runs exactly one step from zero state)
  const float* bih_b = (const float*)d_in[8];
  const float* bhh_b = (const float*)d_in[9];
  const float* fc1w  = (const float*)d_in[10];
  const float* fc1b  = (const float*)d_in[11];
  const float* fc2w  = (const float*)d_in[12];
  const float* fc2b  = (const float*)d_in[13];
  float* out = (float*)d_out;

  // workspace layout
  char* ws = (char*)d_ws;
  u16*  xp = (u16*)ws;                                   // 512*64*1024*2 = 64 MiB
  u32*  Wp = (u32*)(ws + (size_t)T_LEN * BATCH * G4 * 2); // 512 KiB
  float* hf = (float*)(ws + (size_t)T_LEN * BATCH * G4 * 2 + 32 * 4096 * 4);

  k_prep <<<512, 256, 0, stream>>>(whh_f, Wp);
  k_xproj<<<dim3(16, 512), 256, 0, stream>>>(x, emb, wih_f, bih_f, bhh_f, xp);
  k_lstm <<<BATCH, 1024, 0, stream>>>((const uint4*)Wp, xp, hf);
  k_tail <<<BATCH, 256, 0, stream>>>(x, emb, wih_b, bih_b, bhh_b,
                                     fc1w, fc1b, fc2w, fc2b, hf, out);
}